// Round 7
// baseline (209.495 us; speedup 1.0000x reference)
//
#include <hip/hip_runtime.h>
#include <math.h>

// Problem shape (fixed by the reference)
constexpr int Bn = 512;   // batch
constexpr int Tn = 77;    // text tokens
constexpr int Fn = 12;    // video frames
constexpr int Dn = 512;   // feature dim

typedef float v2f __attribute__((ext_vector_type(2)));

// packed fp32 FMA (gfx90a+): acc = a*b + acc, two lanes of fp32 per op
__device__ __forceinline__ void pk_fma(v2f& acc, v2f a, v2f b) {
  asm("v_pk_fma_f32 %0, %1, %2, %0" : "+v"(acc) : "v"(a), "v"(b));
}

// ---------------- DPP cross-lane helpers (pure VALU) ----------------------
template <int ctrl, int rm>
__device__ __forceinline__ float dpp_add_step(float x) {
  int y = __builtin_amdgcn_update_dpp(0, __float_as_int(x), ctrl, rm, 0xF, true);
  return x + __int_as_float(y);
}

template <int ctrl, int rm>
__device__ __forceinline__ float dpp_min_step(float x) {
  int y = __builtin_amdgcn_update_dpp(__float_as_int(x), __float_as_int(x),
                                      ctrl, rm, 0xF, false);
  return fminf(x, __int_as_float(y));
}
template <int ctrl, int rm>
__device__ __forceinline__ float dpp_max_step(float x) {
  int y = __builtin_amdgcn_update_dpp(__float_as_int(x), __float_as_int(x),
                                      ctrl, rm, 0xF, false);
  return fmaxf(x, __int_as_float(y));
}

// all-lane sum within each 16-lane row (xor1, xor2, half_mirror, mirror)
__device__ __forceinline__ float sum16_all(float x) {
  x = dpp_add_step<0xB1, 0xF>(x);   // quad_perm [1,0,3,2]
  x = dpp_add_step<0x4E, 0xF>(x);   // quad_perm [2,3,0,1]
  x = dpp_add_step<0x141, 0xF>(x);  // row_half_mirror
  x = dpp_add_step<0x140, 0xF>(x);  // row_mirror -> per-16 totals (all lanes)
  return x;
}

__device__ __forceinline__ float wave_min63(float x) {
  x = dpp_min_step<0xB1, 0xF>(x);
  x = dpp_min_step<0x4E, 0xF>(x);
  x = dpp_min_step<0x141, 0xF>(x);
  x = dpp_min_step<0x140, 0xF>(x);
  x = dpp_min_step<0x142, 0xA>(x);  // row_bcast15
  x = dpp_min_step<0x143, 0xC>(x);  // row_bcast31
  return x;                         // lane 63 = total
}
__device__ __forceinline__ float wave_max63(float x) {
  x = dpp_max_step<0xB1, 0xF>(x);
  x = dpp_max_step<0x4E, 0xF>(x);
  x = dpp_max_step<0x141, 0xF>(x);
  x = dpp_max_step<0x140, 0xF>(x);
  x = dpp_max_step<0x142, 0xA>(x);
  x = dpp_max_step<0x143, 0xC>(x);
  return x;
}

// ---- order-preserving float<->uint bijection (monotone for ALL floats) ----
// ordf(x) < ordf(y)  <=>  x < y. Both ordf(x) and ~ordf(x) are > 0 for any
// finite x, so 0 is an identity element for atomicMax on either encoding
// (=> a single memset-0 initializes both the running-max and running-min).
__device__ __forceinline__ unsigned ordf(float x) {
  int b = __float_as_int(x);
  return (unsigned)(b ^ ((b >> 31) | 0x80000000));
}
__device__ __forceinline__ float unordf(unsigned u) {
  int b = (u & 0x80000000u) ? (int)(u ^ 0x80000000u) : ~(int)u;
  return __int_as_float(b);
}

// -------------------- Fused single-dispatch kernel -------------------------
// 512 blocks (1/batch) x 256 threads (4 waves). Phase 1 is byte-identical to
// the verified r3 minmax kernel. Then a plain-launch spin barrier:
//   - each block publishes its (bmin,bmax) via 2 device-scope atomicMax on
//     order-encoded uints (~ord for the min), then release-increments ctrl[0].
//   - tid0 spins on ctrl[0]==512 (acquire, s_sleep-polite), reads the 2
//     encoded scalars, LDS-broadcasts.
// SAFETY (why spinning cannot deadlock): grid = 512 = 256 CU x 2;
// __launch_bounds__(256,2) caps VGPR<=256 (2 blocks/CU schedulable) and LDS
// is 32.8KB (4 blocks/CU) => all 512 blocks are resident before any spins.
// All cross-block state is 3 atomic words (no shared arrays => no per-XCD-L2
// false-sharing hazard). ctrl[] zeroed by a 12B hipMemsetAsync per launch.
__global__ __launch_bounds__(256, 2) void
fused_kernel(const float* __restrict__ text,
             const float* __restrict__ video,
             unsigned* __restrict__ ctrl,   // [0]=counter [1]=max_enc [2]=min_enc
             float* __restrict__ out) {
  const int b    = blockIdx.x;
  const int tid  = threadIdx.x;
  const int wv   = tid >> 6;
  const int lane = tid & 63;
  const int g    = lane >> 4;   // frame group: frames 3g..3g+2
  const int k    = lane & 15;   // K-slice [32k, 32k+32)

  // 4 row-slots per wave, 2048 B each (16 K-slices x 128 B, XOR-swizzled)
  __shared__ __align__(16) char lds[4][4 * 2048];
  __shared__ float smin[4], smax[4];
  __shared__ float sgl[2];
  char* my = lds[wv];

  // ---- video: 3 frames x 32 floats per lane, normalize in-register --------
  const float* vb = video + (size_t)b * (Fn * Dn) + k * 32;
  float4 vf[3][8];
#pragma unroll
  for (int m = 0; m < 3; ++m) {
    const float* vr = vb + (size_t)(3 * g + m) * Dn;
#pragma unroll
    for (int j = 0; j < 8; ++j) vf[m][j] = *(const float4*)(vr + 4 * j);
  }
#pragma unroll
  for (int m = 0; m < 3; ++m) {
    v2f nn = (v2f){0.f, 0.f};
#pragma unroll
    for (int j = 0; j < 8; ++j) {
      pk_fma(nn, (v2f){vf[m][j].x, vf[m][j].y}, (v2f){vf[m][j].x, vf[m][j].y});
      pk_fma(nn, (v2f){vf[m][j].z, vf[m][j].w}, (v2f){vf[m][j].z, vf[m][j].w});
    }
    float s = sum16_all(nn.x + nn.y);  // sum over k within the 16-lane group
    float inv = rsqrtf(s);
#pragma unroll
    for (int j = 0; j < 8; ++j) {
      vf[m][j].x *= inv; vf[m][j].y *= inv;
      vf[m][j].z *= inv; vf[m][j].w *= inv;
    }
  }

  // ---- LDS addressing ------------------------------------------------------
  // Storage invariant: row float m = 32K + 4J + e lives at byte
  //   K*128 + ((J ^ (K&7)) << 4) + 4e.
  const int kw = lane >> 3, jw = lane & 7;
  const int wbase = kw * 128 + ((jw ^ (kw & 7)) << 4);
  int rb[8];
#pragma unroll
  for (int j = 0; j < 8; ++j) rb[j] = k * 128 + ((j ^ (k & 7)) << 4);

  // ---- text row streaming: depth-4 register ring ---------------------------
  const float4* tb = (const float4*)(text + (size_t)b * (Tn * Dn));
  const int ni = (76 - wv) / 4 + 1;  // rows per wave: 20,19,19,19

  float4 A0 = tb[(wv + 0)  * 128 + lane], A1 = tb[(wv + 0)  * 128 + 64 + lane];
  float4 B0 = tb[(wv + 4)  * 128 + lane], B1 = tb[(wv + 4)  * 128 + 64 + lane];
  float4 C0 = tb[(wv + 8)  * 128 + lane], C1 = tb[(wv + 8)  * 128 + 64 + lane];
  float4 D0 = tb[(wv + 12) * 128 + lane], D1 = tb[(wv + 12) * 128 + 64 + lane];

  // prologue: row 0 -> slot 0
  *(float4*)(my + wbase)        = A0;
  *(float4*)(my + wbase + 1024) = A1;

  float lmin = 1e30f, lmax = -1e30f;
  int i = 0;

#define BODY(S, W0, W1, L0, L1)                                                \
  do {                                                                         \
    *(float4*)(my + wbase + (((S) + 1) & 3) * 2048)        = W0;               \
    *(float4*)(my + wbase + (((S) + 1) & 3) * 2048 + 1024) = W1;               \
    int rr_ = wv + 4 * (i + 4); if (rr_ > 76) rr_ = 76;                        \
    L0 = tb[rr_ * 128 + lane]; L1 = tb[rr_ * 128 + 64 + lane];                 \
    v2f d0_ = (v2f){0.f, 0.f}, d1_ = d0_, d2_ = d0_, nn_ = d0_;                \
    _Pragma("unroll")                                                          \
    for (int j = 0; j < 8; ++j) {                                              \
      float4 t4 = *(const float4*)(my + rb[j] + (S) * 2048);                   \
      v2f tlo = (v2f){t4.x, t4.y}, thi = (v2f){t4.z, t4.w};                    \
      pk_fma(nn_, tlo, tlo);                                                   \
      pk_fma(nn_, thi, thi);                                                   \
      pk_fma(d0_, tlo, (v2f){vf[0][j].x, vf[0][j].y});                         \
      pk_fma(d0_, thi, (v2f){vf[0][j].z, vf[0][j].w});                         \
      pk_fma(d1_, tlo, (v2f){vf[1][j].x, vf[1][j].y});                         \
      pk_fma(d1_, thi, (v2f){vf[1][j].z, vf[1][j].w});                         \
      pk_fma(d2_, tlo, (v2f){vf[2][j].x, vf[2][j].y});                         \
      pk_fma(d2_, thi, (v2f){vf[2][j].z, vf[2][j].w});                         \
    }                                                                          \
    float sn_ = sum16_all(nn_.x + nn_.y);                                      \
    float s0_ = sum16_all(d0_.x + d0_.y);                                      \
    float s1_ = sum16_all(d1_.x + d1_.y);                                      \
    float s2_ = sum16_all(d2_.x + d2_.y);                                      \
    float invt_ = rsqrtf(sn_);                                                 \
    float e0_ = 1.0f - s0_ * invt_;                                            \
    float e1_ = 1.0f - s1_ * invt_;                                            \
    float e2_ = 1.0f - s2_ * invt_;                                            \
    lmin = fminf(lmin, fminf(e0_, fminf(e1_, e2_)));                           \
    lmax = fmaxf(lmax, fmaxf(e0_, fmaxf(e1_, e2_)));                           \
  } while (0)

  while (i + 4 <= ni) {
    BODY(0, B0, B1, A0, A1); ++i;
    BODY(1, C0, C1, B0, B1); ++i;
    BODY(2, D0, D1, C0, C1); ++i;
    BODY(3, A0, A1, D0, D1); ++i;
  }
  if (i < ni) { BODY(0, B0, B1, A0, A1); ++i; }
  if (i < ni) { BODY(1, C0, C1, B0, B1); ++i; }
  if (i < ni) { BODY(2, D0, D1, C0, C1); ++i; }
#undef BODY

  // block-level reduce: every lane holds a valid (dup-safe) stream
  lmin = wave_min63(lmin);
  lmax = wave_max63(lmax);
  if (lane == 63) { smin[wv] = lmin; smax[wv] = lmax; }
  __syncthreads();
  const float bmn = fminf(fminf(smin[0], smin[1]), fminf(smin[2], smin[3]));
  const float bmx = fmaxf(fmaxf(smax[0], smax[1]), fmaxf(smax[2], smax[3]));

  // ---- publish block scalars + spin barrier (device-scope atomics) --------
  if (tid == 0) {
    atomicMax(ctrl + 1, ordf(bmx));    // running global max (encoded)
    atomicMax(ctrl + 2, ~ordf(bmn));   // running global min (encoded, flipped)
    __threadfence();                   // publish before counting
    __hip_atomic_fetch_add(ctrl, 1u, __ATOMIC_RELEASE,
                           __HIP_MEMORY_SCOPE_AGENT);
    while (__hip_atomic_load(ctrl, __ATOMIC_ACQUIRE,
                             __HIP_MEMORY_SCOPE_AGENT) < (unsigned)Bn) {
      __builtin_amdgcn_s_sleep(8);
    }
    unsigned gx = __hip_atomic_load(ctrl + 1, __ATOMIC_RELAXED,
                                    __HIP_MEMORY_SCOPE_AGENT);
    unsigned gn = __hip_atomic_load(ctrl + 2, __ATOMIC_RELAXED,
                                    __HIP_MEMORY_SCOPE_AGENT);
    sgl[0] = unordf(~gn);   // global min
    sgl[1] = unordf(gx);    // global max
  }
  __syncthreads();

  // ---- write this block's output row (lo/hi from local registers) ---------
  const float gmn = sgl[0], gmx = sgl[1];
  const float inv = 1.0f / (gmx - gmn);
  const float lo  = (bmn - gmn) * inv;   // diagonal value of row b
  const float hi  = (bmx - gmn) * inv;   // off-diagonal value of row b

  const int c = tid * 2;
  float2 v = make_float2(hi, hi);
  if (c == b)     v.x = lo;
  if (c + 1 == b) v.y = lo;
  ((float2*)(out + (size_t)b * Bn))[tid] = v;
}

extern "C" void kernel_launch(void* const* d_in, const int* in_sizes, int n_in,
                              void* d_out, int out_size, void* d_ws, size_t ws_size,
                              hipStream_t stream) {
  const float* text  = (const float*)d_in[0];   // [512,77,512] f32
  const float* video = (const float*)d_in[1];   // [512,12,512] f32
  float* out = (float*)d_out;                   // [512,512] f32
  unsigned* ctrl = (unsigned*)d_ws;             // [0]=ctr [1]=max_e [2]=min_e

  // zero the 3 control words (0 is the identity for both encodings)
  hipMemsetAsync(ctrl, 0, 12, stream);
  fused_kernel<<<Bn, 256, 0, stream>>>(text, video, ctrl, out);
}

// Round 10
// 132.888 us; speedup vs baseline: 1.5765x; 1.5765x over previous
//
#include <hip/hip_runtime.h>
#include <math.h>

// Problem shape (fixed by the reference)
constexpr int Bn = 512;   // batch
constexpr int Tn = 77;    // text tokens
constexpr int Fn = 12;    // video frames
constexpr int Dn = 512;   // feature dim

typedef float v2f __attribute__((ext_vector_type(2)));

// packed fp32 FMA (gfx90a+): acc = a*b + acc, two lanes of fp32 per op
__device__ __forceinline__ void pk_fma(v2f& acc, v2f a, v2f b) {
  asm("v_pk_fma_f32 %0, %1, %2, %0" : "+v"(acc) : "v"(a), "v"(b));
}

// ---------------- DPP cross-lane helpers (pure VALU) ----------------------
template <int ctrl, int rm>
__device__ __forceinline__ float dpp_add_step(float x) {
  int y = __builtin_amdgcn_update_dpp(0, __float_as_int(x), ctrl, rm, 0xF, true);
  return x + __int_as_float(y);
}

template <int ctrl, int rm>
__device__ __forceinline__ float dpp_min_step(float x) {
  int y = __builtin_amdgcn_update_dpp(__float_as_int(x), __float_as_int(x),
                                      ctrl, rm, 0xF, false);
  return fminf(x, __int_as_float(y));
}
template <int ctrl, int rm>
__device__ __forceinline__ float dpp_max_step(float x) {
  int y = __builtin_amdgcn_update_dpp(__float_as_int(x), __float_as_int(x),
                                      ctrl, rm, 0xF, false);
  return fmaxf(x, __int_as_float(y));
}

// all-lane sum within each 16-lane row (xor1, xor2, half_mirror, mirror)
__device__ __forceinline__ float sum16_all(float x) {
  x = dpp_add_step<0xB1, 0xF>(x);   // quad_perm [1,0,3,2]
  x = dpp_add_step<0x4E, 0xF>(x);   // quad_perm [2,3,0,1]
  x = dpp_add_step<0x141, 0xF>(x);  // row_half_mirror
  x = dpp_add_step<0x140, 0xF>(x);  // row_mirror -> per-16 totals (all lanes)
  return x;
}

__device__ __forceinline__ float wave_min63(float x) {
  x = dpp_min_step<0xB1, 0xF>(x);
  x = dpp_min_step<0x4E, 0xF>(x);
  x = dpp_min_step<0x141, 0xF>(x);
  x = dpp_min_step<0x140, 0xF>(x);
  x = dpp_min_step<0x142, 0xA>(x);  // row_bcast15
  x = dpp_min_step<0x143, 0xC>(x);  // row_bcast31
  return x;                         // lane 63 = total
}
__device__ __forceinline__ float wave_max63(float x) {
  x = dpp_max_step<0xB1, 0xF>(x);
  x = dpp_max_step<0x4E, 0xF>(x);
  x = dpp_max_step<0x141, 0xF>(x);
  x = dpp_max_step<0x140, 0xF>(x);
  x = dpp_max_step<0x142, 0xA>(x);
  x = dpp_max_step<0x143, 0xC>(x);
  return x;
}

// -------------------- Kernel A: per-batch dmin/dmax ------------------------
// 1024 blocks (2/batch: b = blockIdx.x>>1, half = blockIdx.x&1) x 256
// threads (4 waves). Grid 1024 = 256 CU x 4 co-resident (r7 counters showed
// VGPR=92, LDS 32.8KB => LDS-limited 4 blocks/CU; the old 512-block grid
// left half the CU capacity empty at 2 waves/SIMD -- too little TLP to hide
// the serial DPP chains + ds_read latency).
// Lane (g = lane>>4, k = lane&15): g owns frames 3g..3g+2 (video slices in
// 96 VGPRs, normalized in-register), k owns the 32-float K-slice [32k,32k+32).
// Wave wv streams text rows s, s+8, s+16, ... where s = 4*half + wv
// (ni = 9..10 rows >= ring depth 4). Rows go global->reg (depth-4 ring,
// coalesced float4) -> ds_write_b128 -> swizzled ds_read_b128 (XOR
// (j^(k&7))<<4: reads 2-way = free). Per row: 3 dots + ||t||^2 each reduced
// with ONE 4-step sum16_all.
// NOTE (r6/r7 evidence): do NOT fuse the output pass into this kernel.
// Cooperative launch doesn't graph-capture here (r6: output never written),
// and an atomic spin barrier costs ~90us in agent-scope cache-maintenance
// traffic (r7: 120us fused vs ~30us for the two plain dispatches).
__global__ __launch_bounds__(256, 2) void
minmax_kernel(const float* __restrict__ text,
              const float* __restrict__ video,
              float* __restrict__ dminb,    // [1024], indexed by blockIdx.x
              float* __restrict__ dmaxb) {  // [1024]
  const int b    = blockIdx.x >> 1;
  const int half = blockIdx.x & 1;
  const int wv   = threadIdx.x >> 6;
  const int lane = threadIdx.x & 63;
  const int g    = lane >> 4;   // frame group: frames 3g..3g+2
  const int k    = lane & 15;   // K-slice [32k, 32k+32)

  // 4 row-slots per wave, 2048 B each (16 K-slices x 128 B, XOR-swizzled)
  __shared__ __align__(16) char lds[4][4 * 2048];
  __shared__ float smin[4], smax[4];
  char* my = lds[wv];

  // ---- video: 3 frames x 32 floats per lane, normalize in-register --------
  // (fetched by both halves of a batch: +12MB total, largely L2-absorbed)
  const float* vb = video + (size_t)b * (Fn * Dn) + k * 32;
  float4 vf[3][8];
#pragma unroll
  for (int m = 0; m < 3; ++m) {
    const float* vr = vb + (size_t)(3 * g + m) * Dn;
#pragma unroll
    for (int j = 0; j < 8; ++j) vf[m][j] = *(const float4*)(vr + 4 * j);
  }
#pragma unroll
  for (int m = 0; m < 3; ++m) {
    v2f nn = (v2f){0.f, 0.f};
#pragma unroll
    for (int j = 0; j < 8; ++j) {
      pk_fma(nn, (v2f){vf[m][j].x, vf[m][j].y}, (v2f){vf[m][j].x, vf[m][j].y});
      pk_fma(nn, (v2f){vf[m][j].z, vf[m][j].w}, (v2f){vf[m][j].z, vf[m][j].w});
    }
    float s = sum16_all(nn.x + nn.y);  // sum over k within the 16-lane group
    float inv = rsqrtf(s);
#pragma unroll
    for (int j = 0; j < 8; ++j) {
      vf[m][j].x *= inv; vf[m][j].y *= inv;
      vf[m][j].z *= inv; vf[m][j].w *= inv;
    }
  }

  // ---- LDS addressing ------------------------------------------------------
  // Storage invariant: row float m = 32K + 4J + e lives at byte
  //   K*128 + ((J ^ (K&7)) << 4) + 4e.
  // Write side: lane l holds floats [4l,4l+4) (c0) and [256+4l,...) (c1):
  //   K = l>>3 (and 8+(l>>3)), J = l&7  ->  same XOR term, +1024 for c1.
  const int kw = lane >> 3, jw = lane & 7;
  const int wbase = kw * 128 + ((jw ^ (kw & 7)) << 4);
  // Read side: lane k, j-th float4 of its slice.
  int rb[8];
#pragma unroll
  for (int j = 0; j < 8; ++j) rb[j] = k * 128 + ((j ^ (k & 7)) << 4);

  // ---- text row streaming: depth-4 register ring, stride-8 streams --------
  const float4* tb = (const float4*)(text + (size_t)b * (Tn * Dn));
  const int s  = 4 * half + wv;        // stream start row, 0..7
  const int ni = (76 - s) / 8 + 1;     // rows in this stream: 10 (s<5) or 9

  float4 A0 = tb[(s + 0)  * 128 + lane], A1 = tb[(s + 0)  * 128 + 64 + lane];
  float4 B0 = tb[(s + 8)  * 128 + lane], B1 = tb[(s + 8)  * 128 + 64 + lane];
  float4 C0 = tb[(s + 16) * 128 + lane], C1 = tb[(s + 16) * 128 + 64 + lane];
  float4 D0 = tb[(s + 24) * 128 + lane], D1 = tb[(s + 24) * 128 + 64 + lane];

  // prologue: row 0 of the stream -> slot 0
  *(float4*)(my + wbase)        = A0;
  *(float4*)(my + wbase + 1024) = A1;

  float lmin = 1e30f, lmax = -1e30f;
  int i = 0;

  // BODY(S): slot S = i&3 (compile-time). Writes row i+1 (regs W*) to slot
  // (S+1)&3, loads row i+4 (clamped dup of 76 on tail -- staged, never read)
  // into regs L*, then reads row i from slot S and accumulates min/max.
#define BODY(S, W0, W1, L0, L1)                                                \
  do {                                                                         \
    *(float4*)(my + wbase + (((S) + 1) & 3) * 2048)        = W0;               \
    *(float4*)(my + wbase + (((S) + 1) & 3) * 2048 + 1024) = W1;               \
    int rr_ = s + 8 * (i + 4); if (rr_ > 76) rr_ = 76;                         \
    L0 = tb[rr_ * 128 + lane]; L1 = tb[rr_ * 128 + 64 + lane];                 \
    v2f d0_ = (v2f){0.f, 0.f}, d1_ = d0_, d2_ = d0_, nn_ = d0_;                \
    _Pragma("unroll")                                                          \
    for (int j = 0; j < 8; ++j) {                                              \
      float4 t4 = *(const float4*)(my + rb[j] + (S) * 2048);                   \
      v2f tlo = (v2f){t4.x, t4.y}, thi = (v2f){t4.z, t4.w};                    \
      pk_fma(nn_, tlo, tlo);                                                   \
      pk_fma(nn_, thi, thi);                                                   \
      pk_fma(d0_, tlo, (v2f){vf[0][j].x, vf[0][j].y});                         \
      pk_fma(d0_, thi, (v2f){vf[0][j].z, vf[0][j].w});                         \
      pk_fma(d1_, tlo, (v2f){vf[1][j].x, vf[1][j].y});                         \
      pk_fma(d1_, thi, (v2f){vf[1][j].z, vf[1][j].w});                         \
      pk_fma(d2_, tlo, (v2f){vf[2][j].x, vf[2][j].y});                         \
      pk_fma(d2_, thi, (v2f){vf[2][j].z, vf[2][j].w});                         \
    }                                                                          \
    float sn_ = sum16_all(nn_.x + nn_.y);                                      \
    float s0_ = sum16_all(d0_.x + d0_.y);                                      \
    float s1_ = sum16_all(d1_.x + d1_.y);                                      \
    float s2_ = sum16_all(d2_.x + d2_.y);                                      \
    float invt_ = rsqrtf(sn_);                                                 \
    float e0_ = 1.0f - s0_ * invt_;                                            \
    float e1_ = 1.0f - s1_ * invt_;                                            \
    float e2_ = 1.0f - s2_ * invt_;                                            \
    lmin = fminf(lmin, fminf(e0_, fminf(e1_, e2_)));                           \
    lmax = fmaxf(lmax, fmaxf(e0_, fmaxf(e1_, e2_)));                           \
  } while (0)

  while (i + 4 <= ni) {
    BODY(0, B0, B1, A0, A1); ++i;
    BODY(1, C0, C1, B0, B1); ++i;
    BODY(2, D0, D1, C0, C1); ++i;
    BODY(3, A0, A1, D0, D1); ++i;
  }
  if (i < ni) { BODY(0, B0, B1, A0, A1); ++i; }
  if (i < ni) { BODY(1, C0, C1, B0, B1); ++i; }
  if (i < ni) { BODY(2, D0, D1, C0, C1); ++i; }
#undef BODY

  // every lane holds a valid (possibly duplicated) stream -> full wave reduce
  lmin = wave_min63(lmin);
  lmax = wave_max63(lmax);
  if (lane == 63) { smin[wv] = lmin; smax[wv] = lmax; }
  __syncthreads();
  if (threadIdx.x == 0) {
    dminb[blockIdx.x] = fminf(fminf(smin[0], smin[1]), fminf(smin[2], smin[3]));
    dmaxb[blockIdx.x] = fmaxf(fmaxf(smax[0], smax[1]), fmaxf(smax[2], smax[3]));
  }
}

// ---- Kernel B: global-scalar reduction + 512x512 output write -------------
// 512 blocks (1 per output row) x 256 threads. Each block redundantly
// reduces the 1024-entry dminb/dmaxb arrays (L2-resident) and writes its
// row. Row b's values combine its two half-blocks (2b, 2b+1). Cross-kernel
// visibility is guaranteed by the dispatch boundary -- no fences needed.
__global__ __launch_bounds__(256) void
out_kernel(const float* __restrict__ dminb,
           const float* __restrict__ dmaxb,
           float* __restrict__ out) {
  const int b    = blockIdx.x;
  const int tid  = threadIdx.x;
  const int wave = tid >> 6;
  const int lane = tid & 63;

  float mn = fminf(fminf(dminb[tid], dminb[tid + 256]),
                   fminf(dminb[tid + 512], dminb[tid + 768]));
  float mx = fmaxf(fmaxf(dmaxb[tid], dmaxb[tid + 256]),
                   fmaxf(dmaxb[tid + 512], dmaxb[tid + 768]));
  mn = wave_min63(mn);
  mx = wave_max63(mx);

  __shared__ float smin[4], smax[4];
  if (lane == 63) { smin[wave] = mn; smax[wave] = mx; }
  __syncthreads();
  mn = fminf(fminf(smin[0], smin[1]), fminf(smin[2], smin[3]));
  mx = fmaxf(fmaxf(smax[0], smax[1]), fmaxf(smax[2], smax[3]));

  const float inv = 1.0f / (mx - mn);
  const float bmn = fminf(dminb[2 * b], dminb[2 * b + 1]);
  const float bmx = fmaxf(dmaxb[2 * b], dmaxb[2 * b + 1]);
  const float lo  = (bmn - mn) * inv;   // diagonal value of row b
  const float hi  = (bmx - mn) * inv;   // off-diagonal value of row b

  const int c = tid * 2;
  float2 v = make_float2(hi, hi);
  if (c == b)     v.x = lo;
  if (c + 1 == b) v.y = lo;
  ((float2*)(out + (size_t)b * Bn))[tid] = v;
}

extern "C" void kernel_launch(void* const* d_in, const int* in_sizes, int n_in,
                              void* d_out, int out_size, void* d_ws, size_t ws_size,
                              hipStream_t stream) {
  const float* text  = (const float*)d_in[0];   // [512,77,512] f32
  const float* video = (const float*)d_in[1];   // [512,12,512] f32
  float* out = (float*)d_out;                   // [512,512] f32
  float* ws  = (float*)d_ws;
  float* dminb = ws;           // [1024]
  float* dmaxb = ws + 1024;    // [1024]

  minmax_kernel<<<2 * Bn, 256, 0, stream>>>(text, video, dminb, dmaxb);
  out_kernel<<<Bn, 256, 0, stream>>>(dminb, dmaxb, out);
}

// Round 11
// 129.693 us; speedup vs baseline: 1.6153x; 1.0246x over previous
//
#include <hip/hip_runtime.h>
#include <math.h>

// Problem shape (fixed by the reference)
constexpr int Bn = 512;   // batch
constexpr int Tn = 77;    // text tokens
constexpr int Fn = 12;    // video frames
constexpr int Dn = 512;   // feature dim

typedef float v2f __attribute__((ext_vector_type(2)));

// packed fp32 FMA (gfx90a+): acc = a*b + acc, two lanes of fp32 per op
__device__ __forceinline__ void pk_fma(v2f& acc, v2f a, v2f b) {
  asm("v_pk_fma_f32 %0, %1, %2, %0" : "+v"(acc) : "v"(a), "v"(b));
}

// ---------------- DPP cross-lane helpers (pure VALU) ----------------------
template <int ctrl, int rm>
__device__ __forceinline__ float dpp_add_step(float x) {
  int y = __builtin_amdgcn_update_dpp(0, __float_as_int(x), ctrl, rm, 0xF, true);
  return x + __int_as_float(y);
}

template <int ctrl, int rm>
__device__ __forceinline__ float dpp_min_step(float x) {
  int y = __builtin_amdgcn_update_dpp(__float_as_int(x), __float_as_int(x),
                                      ctrl, rm, 0xF, false);
  return fminf(x, __int_as_float(y));
}
template <int ctrl, int rm>
__device__ __forceinline__ float dpp_max_step(float x) {
  int y = __builtin_amdgcn_update_dpp(__float_as_int(x), __float_as_int(x),
                                      ctrl, rm, 0xF, false);
  return fmaxf(x, __int_as_float(y));
}

// all-lane sum within each 16-lane row (xor1, xor2, half_mirror, mirror)
__device__ __forceinline__ float sum16_all(float x) {
  x = dpp_add_step<0xB1, 0xF>(x);   // quad_perm [1,0,3,2]
  x = dpp_add_step<0x4E, 0xF>(x);   // quad_perm [2,3,0,1]
  x = dpp_add_step<0x141, 0xF>(x);  // row_half_mirror
  x = dpp_add_step<0x140, 0xF>(x);  // row_mirror -> per-16 totals (all lanes)
  return x;
}

__device__ __forceinline__ float wave_min63(float x) {
  x = dpp_min_step<0xB1, 0xF>(x);
  x = dpp_min_step<0x4E, 0xF>(x);
  x = dpp_min_step<0x141, 0xF>(x);
  x = dpp_min_step<0x140, 0xF>(x);
  x = dpp_min_step<0x142, 0xA>(x);  // row_bcast15
  x = dpp_min_step<0x143, 0xC>(x);  // row_bcast31
  return x;                         // lane 63 = total
}
__device__ __forceinline__ float wave_max63(float x) {
  x = dpp_max_step<0xB1, 0xF>(x);
  x = dpp_max_step<0x4E, 0xF>(x);
  x = dpp_max_step<0x141, 0xF>(x);
  x = dpp_max_step<0x140, 0xF>(x);
  x = dpp_max_step<0x142, 0xA>(x);
  x = dpp_max_step<0x143, 0xC>(x);
  return x;
}

// -------------------- Kernel A: per-batch dmin/dmax ------------------------
// 512 blocks (1/batch) x 256 threads (4 waves, independent; no in-loop sync).
// Lane (g = lane>>4, k = lane&15): g owns frames 3g..3g+2 (video slices in
// 96 VGPRs, normalized in-register), k owns the 32-float K-slice [32k,32k+32).
// Text rows stream global->reg (depth-4 ring, coalesced float4) ->
// ds_write_b128 -> swizzled ds_read_b128 (XOR (j^(k&7))<<4: reads 2-way =
// free). Per row: 3 dots + ||t||^2 each reduced with ONE 4-step sum16_all
// (16 DPP ops total). All staging is compiler-visible (counted waitcnts are
// auto-inserted; same-wave DS-pipe order makes write->read safe).
// MEASURED DEAD ENDS (do not revisit):
//  - r6: cooperative-launch fusion -- not graph-capturable (output unwritten).
//  - r7: atomic-spin-barrier fusion -- ~90us agent-scope cache-op stalls.
//  - r10: 2 blocks/batch (4/CU TLP) -- null/negative; doubled video prologue
//    cancels the latency-hiding gain (130.8 -> 132.9us).
__global__ __launch_bounds__(256, 2) void
minmax_kernel(const float* __restrict__ text,
              const float* __restrict__ video,
              float* __restrict__ dminb,
              float* __restrict__ dmaxb) {
  const int b    = blockIdx.x;
  const int wv   = threadIdx.x >> 6;
  const int lane = threadIdx.x & 63;
  const int g    = lane >> 4;   // frame group: frames 3g..3g+2
  const int k    = lane & 15;   // K-slice [32k, 32k+32)

  // 4 row-slots per wave, 2048 B each (16 K-slices x 128 B, XOR-swizzled)
  __shared__ __align__(16) char lds[4][4 * 2048];
  __shared__ float smin[4], smax[4];
  char* my = lds[wv];

  // ---- video: 3 frames x 32 floats per lane, normalize in-register --------
  const float* vb = video + (size_t)b * (Fn * Dn) + k * 32;
  float4 vf[3][8];
#pragma unroll
  for (int m = 0; m < 3; ++m) {
    const float* vr = vb + (size_t)(3 * g + m) * Dn;
#pragma unroll
    for (int j = 0; j < 8; ++j) vf[m][j] = *(const float4*)(vr + 4 * j);
  }
#pragma unroll
  for (int m = 0; m < 3; ++m) {
    v2f nn = (v2f){0.f, 0.f};
#pragma unroll
    for (int j = 0; j < 8; ++j) {
      pk_fma(nn, (v2f){vf[m][j].x, vf[m][j].y}, (v2f){vf[m][j].x, vf[m][j].y});
      pk_fma(nn, (v2f){vf[m][j].z, vf[m][j].w}, (v2f){vf[m][j].z, vf[m][j].w});
    }
    float s = sum16_all(nn.x + nn.y);  // sum over k within the 16-lane group
    float inv = rsqrtf(s);
#pragma unroll
    for (int j = 0; j < 8; ++j) {
      vf[m][j].x *= inv; vf[m][j].y *= inv;
      vf[m][j].z *= inv; vf[m][j].w *= inv;
    }
  }

  // ---- LDS addressing ------------------------------------------------------
  // Storage invariant: row float m = 32K + 4J + e lives at byte
  //   K*128 + ((J ^ (K&7)) << 4) + 4e.
  // Write side: lane l holds floats [4l,4l+4) (c0) and [256+4l,...) (c1):
  //   K = l>>3 (and 8+(l>>3)), J = l&7  ->  same XOR term, +1024 for c1.
  const int kw = lane >> 3, jw = lane & 7;
  const int wbase = kw * 128 + ((jw ^ (kw & 7)) << 4);
  // Read side: lane k, j-th float4 of its slice.
  int rb[8];
#pragma unroll
  for (int j = 0; j < 8; ++j) rb[j] = k * 128 + ((j ^ (k & 7)) << 4);

  // ---- text row streaming: depth-4 register ring ---------------------------
  const float4* tb = (const float4*)(text + (size_t)b * (Tn * Dn));
  const int ni = (76 - wv) / 4 + 1;  // rows per wave: 20,19,19,19

  float4 A0 = tb[(wv + 0)  * 128 + lane], A1 = tb[(wv + 0)  * 128 + 64 + lane];
  float4 B0 = tb[(wv + 4)  * 128 + lane], B1 = tb[(wv + 4)  * 128 + 64 + lane];
  float4 C0 = tb[(wv + 8)  * 128 + lane], C1 = tb[(wv + 8)  * 128 + 64 + lane];
  float4 D0 = tb[(wv + 12) * 128 + lane], D1 = tb[(wv + 12) * 128 + 64 + lane];

  // prologue: row 0 -> slot 0
  *(float4*)(my + wbase)        = A0;
  *(float4*)(my + wbase + 1024) = A1;

  float lmin = 1e30f, lmax = -1e30f;
  int i = 0;

  // BODY(S): slot S = i&3 (compile-time). Writes row i+1 (regs W*) to slot
  // (S+1)&3, loads row i+4 (clamped dup of 76 on tail -- staged, never read)
  // into regs L*, then reads row i from slot S and accumulates min/max.
#define BODY(S, W0, W1, L0, L1)                                                \
  do {                                                                         \
    *(float4*)(my + wbase + (((S) + 1) & 3) * 2048)        = W0;               \
    *(float4*)(my + wbase + (((S) + 1) & 3) * 2048 + 1024) = W1;               \
    int rr_ = wv + 4 * (i + 4); if (rr_ > 76) rr_ = 76;                        \
    L0 = tb[rr_ * 128 + lane]; L1 = tb[rr_ * 128 + 64 + lane];                 \
    v2f d0_ = (v2f){0.f, 0.f}, d1_ = d0_, d2_ = d0_, nn_ = d0_;                \
    _Pragma("unroll")                                                          \
    for (int j = 0; j < 8; ++j) {                                              \
      float4 t4 = *(const float4*)(my + rb[j] + (S) * 2048);                   \
      v2f tlo = (v2f){t4.x, t4.y}, thi = (v2f){t4.z, t4.w};                    \
      pk_fma(nn_, tlo, tlo);                                                   \
      pk_fma(nn_, thi, thi);                                                   \
      pk_fma(d0_, tlo, (v2f){vf[0][j].x, vf[0][j].y});                         \
      pk_fma(d0_, thi, (v2f){vf[0][j].z, vf[0][j].w});                         \
      pk_fma(d1_, tlo, (v2f){vf[1][j].x, vf[1][j].y});                         \
      pk_fma(d1_, thi, (v2f){vf[1][j].z, vf[1][j].w});                         \
      pk_fma(d2_, tlo, (v2f){vf[2][j].x, vf[2][j].y});                         \
      pk_fma(d2_, thi, (v2f){vf[2][j].z, vf[2][j].w});                         \
    }                                                                          \
    float sn_ = sum16_all(nn_.x + nn_.y);                                      \
    float s0_ = sum16_all(d0_.x + d0_.y);                                      \
    float s1_ = sum16_all(d1_.x + d1_.y);                                      \
    float s2_ = sum16_all(d2_.x + d2_.y);                                      \
    float invt_ = rsqrtf(sn_);                                                 \
    float e0_ = 1.0f - s0_ * invt_;                                            \
    float e1_ = 1.0f - s1_ * invt_;                                            \
    float e2_ = 1.0f - s2_ * invt_;                                            \
    lmin = fminf(lmin, fminf(e0_, fminf(e1_, e2_)));                           \
    lmax = fmaxf(lmax, fmaxf(e0_, fmaxf(e1_, e2_)));                           \
  } while (0)

  while (i + 4 <= ni) {
    BODY(0, B0, B1, A0, A1); ++i;
    BODY(1, C0, C1, B0, B1); ++i;
    BODY(2, D0, D1, C0, C1); ++i;
    BODY(3, A0, A1, D0, D1); ++i;
  }
  if (i < ni) { BODY(0, B0, B1, A0, A1); ++i; }
  if (i < ni) { BODY(1, C0, C1, B0, B1); ++i; }
  if (i < ni) { BODY(2, D0, D1, C0, C1); ++i; }
#undef BODY

  // every lane holds a valid (possibly duplicated) stream -> full wave reduce
  lmin = wave_min63(lmin);
  lmax = wave_max63(lmax);
  if (lane == 63) { smin[wv] = lmin; smax[wv] = lmax; }
  __syncthreads();
  if (threadIdx.x == 0) {
    dminb[b] = fminf(fminf(smin[0], smin[1]), fminf(smin[2], smin[3]));
    dmaxb[b] = fmaxf(fmaxf(smax[0], smax[1]), fmaxf(smax[2], smax[3]));
  }
}

// ---- Kernel B: fused global-scalar reduction + 512x512 output write -------
// 512 blocks (1 per output row) x 256 threads. Each block redundantly
// reduces the 512-entry dminb/dmaxb arrays (L2-resident) and writes its row.
// Cross-kernel visibility of dminb/dmaxb is guaranteed by the dispatch
// boundary (implicit device-scope flush) -- no fences needed.
__global__ __launch_bounds__(256) void
out_kernel(const float* __restrict__ dminb,
           const float* __restrict__ dmaxb,
           float* __restrict__ out) {
  const int b    = blockIdx.x;
  const int tid  = threadIdx.x;
  const int wave = tid >> 6;
  const int lane = tid & 63;

  float mn = fminf(dminb[tid], dminb[tid + 256]);
  float mx = fmaxf(dmaxb[tid], dmaxb[tid + 256]);
  mn = wave_min63(mn);
  mx = wave_max63(mx);

  __shared__ float smin[4], smax[4];
  if (lane == 63) { smin[wave] = mn; smax[wave] = mx; }
  __syncthreads();
  mn = fminf(fminf(smin[0], smin[1]), fminf(smin[2], smin[3]));
  mx = fmaxf(fmaxf(smax[0], smax[1]), fmaxf(smax[2], smax[3]));

  const float inv = 1.0f / (mx - mn);
  const float lo  = (dminb[b] - mn) * inv;   // diagonal value of row b
  const float hi  = (dmaxb[b] - mn) * inv;   // off-diagonal value of row b

  const int c = tid * 2;
  float2 v = make_float2(hi, hi);
  if (c == b)     v.x = lo;
  if (c + 1 == b) v.y = lo;
  ((float2*)(out + (size_t)b * Bn))[tid] = v;
}

extern "C" void kernel_launch(void* const* d_in, const int* in_sizes, int n_in,
                              void* d_out, int out_size, void* d_ws, size_t ws_size,
                              hipStream_t stream) {
  const float* text  = (const float*)d_in[0];   // [512,77,512] f32
  const float* video = (const float*)d_in[1];   // [512,12,512] f32
  float* out = (float*)d_out;                   // [512,512] f32
  float* ws  = (float*)d_ws;
  float* dminb = ws;          // [512]
  float* dmaxb = ws + 512;    // [512]

  minmax_kernel<<<Bn, 256, 0, stream>>>(text, video, dminb, dmaxb);
  out_kernel<<<Bn, 256, 0, stream>>>(dminb, dmaxb, out);
}